// Round 7
// baseline (534.227 us; speedup 1.0000x reference)
//
#include <hip/hip_runtime.h>
#include <math.h>

#define NNODES 38400
#define KNBR 8
#define BK 32

typedef __attribute__((ext_vector_type(8))) short bf16x8;
typedef __attribute__((ext_vector_type(4))) short short4v;
typedef __attribute__((ext_vector_type(4))) float f32x4;

// Round-to-nearest-even split of fp32 into hi+lo bf16 (bit patterns).
static __device__ inline void split_bf16(float x, short& hi, short& lo) {
    unsigned u = __float_as_uint(x);
    unsigned r = (u + 0x7FFFu + ((u >> 16) & 1u)) & 0xFFFF0000u;
    hi = (short)(r >> 16);
    float rem = x - __uint_as_float(r);
    unsigned u2 = __float_as_uint(rem);
    unsigned r2 = (u2 + 0x7FFFu + ((u2 >> 16) & 1u));
    lo = (short)(r2 >> 16);
}

// Monotone float<->uint mapping for atomicMax-based float max.
static __device__ inline unsigned fmax_encode(float f) {
    unsigned u = __float_as_uint(f);
    return (u & 0x80000000u) ? ~u : (u | 0x80000000u);
}
static __device__ inline float fmax_decode(unsigned k) {
    return (k & 0x80000000u) ? __uint_as_float(k ^ 0x80000000u)
                             : __uint_as_float(~k);
}

// Swizzled LDS element offset: row r (0..127) of 32 bf16, 16B chunk c (0..3),
// rotated by (r>>1)&3 -> ds_read_b128 across 16 rows is <=2-way (free).
static __device__ inline int lds_off(int r, int c) {
    return r * 32 + (((c + (r >> 1)) & 3) << 3);
}

// ---- MFMA GEMM on pre-split bf16 planes ----------------------------------
__global__ __launch_bounds__(256) void gemm_planes(
    const short* __restrict__ Ahi, const short* __restrict__ Alo, int Kp, int nk,
    const short* __restrict__ Bthi, const short* __restrict__ Btlo,
    const short* __restrict__ Bphi, const short* __restrict__ Bplo,
    int D, float* __restrict__ Y)
{
    const int ldY = 2 * D;
    const int row0 = blockIdx.x * 128;
    const int col0 = blockIdx.y * 128;
    const int tid = threadIdx.x;
    const int lane = tid & 63, wid = tid >> 6;
    const int wm = wid >> 1, wn = wid & 1;

    __shared__ short Ah_s[128 * 32];
    __shared__ short Al_s[128 * 32];
    __shared__ short Bh_s[128 * 32];
    __shared__ short Bl_s[128 * 32];

    const int lr = tid >> 1;
    const int hc = (tid & 1) * 2;

    const short* a_hi_src = Ahi + (size_t)(row0 + lr) * Kp + hc * 8;
    const short* a_lo_src = Alo + (size_t)(row0 + lr) * Kp + hc * 8;
    const int bcol = col0 + lr;
    const short* b_hi_src = nullptr;
    const short* b_lo_src = nullptr;
    if (bcol < D) {
        b_hi_src = Bthi + (size_t)bcol * Kp + hc * 8;
        b_lo_src = Btlo + (size_t)bcol * Kp + hc * 8;
    } else if (bcol < 2 * D) {
        b_hi_src = Bphi + (size_t)(bcol - D) * Kp + hc * 8;
        b_lo_src = Bplo + (size_t)(bcol - D) * Kp + hc * 8;
    }

    bf16x8 rAh[2], rAl[2], rBh[2], rBl[2];

    auto load_tile = [&](int ks) {
        const int ko = ks * BK;
        rAh[0] = *(const bf16x8*)(a_hi_src + ko);
        rAh[1] = *(const bf16x8*)(a_hi_src + ko + 8);
        rAl[0] = *(const bf16x8*)(a_lo_src + ko);
        rAl[1] = *(const bf16x8*)(a_lo_src + ko + 8);
        if (b_hi_src) {
            rBh[0] = *(const bf16x8*)(b_hi_src + ko);
            rBh[1] = *(const bf16x8*)(b_hi_src + ko + 8);
            rBl[0] = *(const bf16x8*)(b_lo_src + ko);
            rBl[1] = *(const bf16x8*)(b_lo_src + ko + 8);
        } else {
            bf16x8 z = {};
            rBh[0] = z; rBh[1] = z; rBl[0] = z; rBl[1] = z;
        }
    };

    f32x4 acc[4][4] = {};
    load_tile(0);

    for (int ks = 0; ks < nk; ++ks) {
        __syncthreads();
        *(bf16x8*)&Ah_s[lds_off(lr, hc)]     = rAh[0];
        *(bf16x8*)&Ah_s[lds_off(lr, hc + 1)] = rAh[1];
        *(bf16x8*)&Al_s[lds_off(lr, hc)]     = rAl[0];
        *(bf16x8*)&Al_s[lds_off(lr, hc + 1)] = rAl[1];
        *(bf16x8*)&Bh_s[lds_off(lr, hc)]     = rBh[0];
        *(bf16x8*)&Bh_s[lds_off(lr, hc + 1)] = rBh[1];
        *(bf16x8*)&Bl_s[lds_off(lr, hc)]     = rBl[0];
        *(bf16x8*)&Bl_s[lds_off(lr, hc + 1)] = rBl[1];
        __syncthreads();
        if (ks + 1 < nk) load_tile(ks + 1);

        const int fr = lane & 15, g = lane >> 4;
        bf16x8 bh[4], bl[4];
#pragma unroll
        for (int f = 0; f < 4; ++f) {
            int bc = wn * 64 + f * 16 + fr;
            bh[f] = *(const bf16x8*)&Bh_s[lds_off(bc, g)];
            bl[f] = *(const bf16x8*)&Bl_s[lds_off(bc, g)];
        }
#pragma unroll
        for (int fm = 0; fm < 4; ++fm) {
            int ar = wm * 64 + fm * 16 + fr;
            bf16x8 ah = *(const bf16x8*)&Ah_s[lds_off(ar, g)];
            bf16x8 al = *(const bf16x8*)&Al_s[lds_off(ar, g)];
#pragma unroll
            for (int fn = 0; fn < 4; ++fn) {
                acc[fm][fn] = __builtin_amdgcn_mfma_f32_16x16x32_bf16(
                    bh[fn], ah, acc[fm][fn], 0, 0, 0);
                acc[fm][fn] = __builtin_amdgcn_mfma_f32_16x16x32_bf16(
                    bl[fn], ah, acc[fm][fn], 0, 0, 0);
                acc[fm][fn] = __builtin_amdgcn_mfma_f32_16x16x32_bf16(
                    bh[fn], al, acc[fm][fn], 0, 0, 0);
            }
        }
    }

#pragma unroll
    for (int fm = 0; fm < 4; ++fm) {
        int row = row0 + wm * 64 + fm * 16 + (lane & 15);
#pragma unroll
        for (int fn = 0; fn < 4; ++fn) {
            int col = col0 + wn * 64 + fn * 16 + (lane >> 4) * 4;
            if (col < ldY)
                *(f32x4*)(Y + (size_t)row * ldY + col) = acc[fm][fn];
        }
    }
}

// ---- split X (fp32 [N][50] -> hi/lo bf16 planes [N][64], zero-padded) ----
__global__ __launch_bounds__(256) void split_x(
    const float* __restrict__ X, short* __restrict__ Hhi, short* __restrict__ Hlo)
{
    const int total = NNODES * 16;
    for (int idx = blockIdx.x * 256 + threadIdx.x; idx < total;
         idx += gridDim.x * 256) {
        int n = idx >> 4, c = (idx & 15) << 2;
        short4v hi, lo;
#pragma unroll
        for (int j = 0; j < 4; ++j) {
            int e = c + j;
            float v = (e < 50) ? X[(size_t)n * 50 + e] : 0.f;
            short h, l; split_bf16(v, h, l);
            hi[j] = h; lo[j] = l;
        }
        *(short4v*)&Hhi[(size_t)n * 64 + c] = hi;
        *(short4v*)&Hlo[(size_t)n * 64 + c] = lo;
    }
}

// ---- split all weight matrices into hi/lo planes -------------------------
struct WSplitArgs {
    const float* w[6]; short* hi[6]; short* lo[6];
    int rows[6], ci[6], kp[6], chunks[6];
    int total;
};
__global__ __launch_bounds__(256) void split_w(WSplitArgs a)
{
    for (int idx = blockIdx.x * 256 + threadIdx.x; idx < a.total;
         idx += gridDim.x * 256) {
        int seg = 0, rem = idx;
        while (rem >= a.chunks[seg]) { rem -= a.chunks[seg]; ++seg; }
        const int kp4 = a.kp[seg] >> 2;
        const int row = rem / kp4;
        const int c = (rem - row * kp4) << 2;
        const int ci = a.ci[seg];
        const float* w = a.w[seg] + (size_t)row * ci;
        short4v hi, lo;
#pragma unroll
        for (int j = 0; j < 4; ++j) {
            int e = c + j;
            float v = (e < ci) ? w[e] : 0.f;
            short h, l; split_bf16(v, h, l);
            hi[j] = h; lo[j] = l;
        }
        size_t o = (size_t)row * a.kp[seg] + c;
        *(short4v*)&a.hi[seg][o] = hi;
        *(short4v*)&a.lo[seg][o] = lo;
    }
}

// ---- EdgeConv epilogue: LDS-staged per (graph, 32-col slice) -------------
// MODE 0 (EMIT): tanh + split -> H planes (slices cover [0,kp), pads zeroed)
// MODE 1 (GMAX): running channel max -> atomicMax into gk[node_local*64+g]
template <int MODE>
__global__ __launch_bounds__(256) void edge_lds(
    const float* __restrict__ Y, int Co, int kp,
    const int* __restrict__ nbr,
    const float* __restrict__ tb, const float* __restrict__ pb,
    short* __restrict__ Hhi, short* __restrict__ Hlo,
    unsigned* __restrict__ gk)
{
    __shared__ float yt[600 * 33];   // pad 33 -> bank (j+d)%32
    const int g = blockIdx.x;
    const int s0 = blockIdx.y * 32;
    const int ldY = 2 * Co;
    const int tid = threadIdx.x;
    const size_t ybase = (size_t)g * 600 * ldY;

    if (s0 < Co) {
        for (int idx = tid; idx < 600 * 8; idx += 256) {
            int n = idx >> 3, c = (idx & 7) << 2;
            int col = s0 + c;
            if (col < Co) {
                float4 v = *(const float4*)(Y + ybase + (size_t)n * ldY + col);
                yt[n * 33 + c]     = v.x;
                yt[n * 33 + c + 1] = v.y;
                yt[n * 33 + c + 2] = v.z;
                yt[n * 33 + c + 3] = v.w;
            }
        }
    }
    __syncthreads();

    for (int n = tid; n < 600; n += 256) {
        const int ng = g * 600 + n;
        int j[KNBR];
#pragma unroll
        for (int k = 0; k < KNBR; ++k) j[k] = nbr[ng * KNBR + k] - g * 600;

        if (MODE == 0) {
#pragma unroll
            for (int d4 = 0; d4 < 8; ++d4) {
                int col = s0 + d4 * 4;
                short4v hi = {}, lo = {};
                if (col < Co) {
#pragma unroll
                    for (int jj = 0; jj < 4; ++jj) {
                        int d = d4 * 4 + jj;       // slice-local
                        int ca = col + jj;         // absolute col
                        float m = -INFINITY;
#pragma unroll
                        for (int k = 0; k < KNBR; ++k)
                            m = fmaxf(m, yt[j[k] * 33 + d]);
                        float ytn = yt[n * 33 + d];
                        float yp = Y[ybase + (size_t)n * ldY + Co + ca];
                        float v = m - ytn + tb[ca] + yp + pb[ca];
                        float o = tanhf(v);
                        short h, l; split_bf16(o, h, l);
                        hi[jj] = h; lo[jj] = l;
                    }
                }
                *(short4v*)&Hhi[(size_t)ng * kp + col] = hi;
                *(short4v*)&Hlo[(size_t)ng * kp + col] = lo;
            }
        } else {
            float mx = -INFINITY;
            for (int d = 0; d < 32; ++d) {
                int ca = s0 + d;
                if (ca >= Co) break;
                float m = -INFINITY;
#pragma unroll
                for (int k = 0; k < KNBR; ++k)
                    m = fmaxf(m, yt[j[k] * 33 + d]);
                float ytn = yt[n * 33 + d];
                float yp = Y[ybase + (size_t)n * ldY + Co + ca];
                mx = fmaxf(mx, m - ytn + tb[ca] + yp + pb[ca]);
            }
            atomicMax(&gk[n * 64 + g], fmax_encode(mx));
        }
    }
}

// ---- FC layer: channel-major activations [CIN][64], block = 4 o x 64 g ---
// ACT 0: tanh, out[o*64+g].  ACT 1: clip, out[g*COUT+o] (row-major final).
template <int CIN, int COUT, int ACT, bool DECODE>
__global__ __launch_bounds__(256) void fc_layer(
    const void* __restrict__ in, const float* __restrict__ w,
    const float* __restrict__ b, float* __restrict__ out)
{
    const int o = blockIdx.x * 4 + (threadIdx.x >> 6);
    const int g = threadIdx.x & 63;
    if (o >= COUT) return;
    const float* inf = (const float*)in;
    const unsigned* inu = (const unsigned*)in;
    float s = b[o];
#pragma unroll 4
    for (int c = 0; c < CIN; ++c) {
        float a = DECODE ? fmax_decode(inu[c * 64 + g]) : inf[c * 64 + g];
        s = fmaf(a, w[o * CIN + c], s);
    }
    if (ACT == 0) out[o * 64 + g] = tanhf(s);
    else out[(size_t)g * COUT + o] = fminf(fmaxf(s, -2.f), 2.f);
}

extern "C" void kernel_launch(void* const* d_in, const int* in_sizes, int n_in,
                              void* d_out, int out_size, void* d_ws, size_t ws_size,
                              hipStream_t stream)
{
    const float* inputs = (const float*)d_in[0];
    const int*   nbr    = (const int*)d_in[1];
    const float* t1w = (const float*)d_in[2];  const float* t1b = (const float*)d_in[3];
    const float* p1w = (const float*)d_in[4];  const float* p1b = (const float*)d_in[5];
    const float* t2w = (const float*)d_in[6];  const float* t2b = (const float*)d_in[7];
    const float* p2w = (const float*)d_in[8];  const float* p2b = (const float*)d_in[9];
    const float* t3w = (const float*)d_in[10]; const float* t3b = (const float*)d_in[11];
    const float* p3w = (const float*)d_in[12]; const float* p3b = (const float*)d_in[13];
    const float* fc1w = (const float*)d_in[14]; const float* fc1b = (const float*)d_in[15];
    const float* fc2w = (const float*)d_in[16]; const float* fc2b = (const float*)d_in[17];
    const float* fc3w = (const float*)d_in[18]; const float* fc3b = (const float*)d_in[19];
    const float* fc4w = (const float*)d_in[20]; const float* fc4b = (const float*)d_in[21];
    const float* fow  = (const float*)d_in[22]; const float* fob  = (const float*)d_in[23];
    float* out = (float*)d_out;

    const int N = NNODES;
    const int Kp1 = 64, Kp2 = 128, Kp3 = 256;
    const int nk3 = 7;   // K=200 -> 224 iterated (pad cols zero)

    char* ws = (char*)d_ws;
    size_t off = 0;
    auto alloc = [&](size_t bytes) {
        void* p = ws + off;
        off = (off + bytes + 255) & ~(size_t)255;
        return p;
    };
    short* Xhi = (short*)alloc((size_t)N * Kp1 * 2);
    short* Xlo = (short*)alloc((size_t)N * Kp1 * 2);
    short* H1hi = (short*)alloc((size_t)N * Kp2 * 2);
    short* H1lo = (short*)alloc((size_t)N * Kp2 * 2);
    short* H2hi = (short*)alloc((size_t)N * Kp3 * 2);
    short* H2lo = (short*)alloc((size_t)N * Kp3 * 2);
    short* Wt1h = (short*)alloc((size_t)100 * Kp1 * 2);
    short* Wt1l = (short*)alloc((size_t)100 * Kp1 * 2);
    short* Wp1h = (short*)alloc((size_t)100 * Kp1 * 2);
    short* Wp1l = (short*)alloc((size_t)100 * Kp1 * 2);
    short* Wt2h = (short*)alloc((size_t)200 * Kp2 * 2);
    short* Wt2l = (short*)alloc((size_t)200 * Kp2 * 2);
    short* Wp2h = (short*)alloc((size_t)200 * Kp2 * 2);
    short* Wp2l = (short*)alloc((size_t)200 * Kp2 * 2);
    short* Wt3h = (short*)alloc((size_t)600 * Kp3 * 2);
    short* Wt3l = (short*)alloc((size_t)600 * Kp3 * 2);
    short* Wp3h = (short*)alloc((size_t)600 * Kp3 * 2);
    short* Wp3l = (short*)alloc((size_t)600 * Kp3 * 2);
    unsigned* gk = (unsigned*)alloc((size_t)600 * 64 * 4);  // [p][b] keys
    float* h1g = (float*)alloc((size_t)300 * 64 * 4);
    float* h2g = (float*)alloc((size_t)300 * 64 * 4);
    float* h3g = (float*)alloc((size_t)100 * 64 * 4);
    float* h4g = (float*)alloc((size_t)50 * 64 * 4);
    float* Y = (float*)(ws + off);
    size_t ybudget = (ws_size > off) ? (ws_size - off) : 0;

    // Layer-3 channel chunk (mult of 32): Y chunk = N*2*Dc*4 bytes, cap 256
    // (78.6 MB, L3-resident between GEMM and its epilogue).
    int Dc = (int)(ybudget / ((size_t)N * 8)) & ~31;
    if (Dc > 256) Dc = 256;
    if (Dc < 32) Dc = 32;

    hipMemsetAsync(gk, 0, (size_t)600 * 64 * 4, stream);  // keys: 0 < all real

    // ---- pre-split weights & input ----
    {
        WSplitArgs a;
        const float* w[6] = {t1w, p1w, t2w, p2w, t3w, p3w};
        short* hi[6] = {Wt1h, Wp1h, Wt2h, Wp2h, Wt3h, Wp3h};
        short* lo[6] = {Wt1l, Wp1l, Wt2l, Wp2l, Wt3l, Wp3l};
        int rows[6] = {100, 100, 200, 200, 600, 600};
        int ci[6]   = {50, 50, 100, 100, 200, 200};
        int kp[6]   = {Kp1, Kp1, Kp2, Kp2, Kp3, Kp3};
        int total = 0;
        for (int i = 0; i < 6; ++i) {
            a.w[i] = w[i]; a.hi[i] = hi[i]; a.lo[i] = lo[i];
            a.rows[i] = rows[i]; a.ci[i] = ci[i]; a.kp[i] = kp[i];
            a.chunks[i] = rows[i] * (kp[i] >> 2);
            total += a.chunks[i];
        }
        a.total = total;
        split_w<<<(total + 255) / 256, 256, 0, stream>>>(a);
        split_x<<<2400, 256, 0, stream>>>(inputs, Xhi, Xlo);
    }

    // ---- EdgeConv 1: K=50(->64), Co=100 ----
    gemm_planes<<<dim3(N / 128, 2), 256, 0, stream>>>(
        Xhi, Xlo, Kp1, Kp1 / BK, Wt1h, Wt1l, Wp1h, Wp1l, 100, Y);
    edge_lds<0><<<dim3(64, Kp2 / 32), 256, 0, stream>>>(
        Y, 100, Kp2, nbr, t1b, p1b, H1hi, H1lo, nullptr);

    // ---- EdgeConv 2: K=100(->128), Co=200 ----
    gemm_planes<<<dim3(N / 128, 4), 256, 0, stream>>>(
        H1hi, H1lo, Kp2, Kp2 / BK, Wt2h, Wt2l, Wp2h, Wp2l, 200, Y);
    edge_lds<0><<<dim3(64, Kp3 / 32), 256, 0, stream>>>(
        Y, 200, Kp3, nbr, t2b, p2b, H2hi, H2lo, nullptr);

    // ---- EdgeConv 3: K=200(224 iterated), Co=600, L3-resident chunks ----
    for (int d0 = 0; d0 < 600; d0 += Dc) {
        int D = (600 - d0 < Dc) ? (600 - d0) : Dc;
        gemm_planes<<<dim3(N / 128, (2 * D + 127) / 128), 256, 0, stream>>>(
            H2hi, H2lo, Kp3, nk3,
            Wt3h + (size_t)d0 * Kp3, Wt3l + (size_t)d0 * Kp3,
            Wp3h + (size_t)d0 * Kp3, Wp3l + (size_t)d0 * Kp3, D, Y);
        edge_lds<1><<<dim3(64, (D + 31) / 32), 256, 0, stream>>>(
            Y, D, 0, nbr, t3b + d0, p3b + d0, nullptr, nullptr, gk);
    }

    // ---- FC head: channel-major chain ----
    fc_layer<600, 300, 0, true ><<<75, 256, 0, stream>>>(gk,  fc1w, fc1b, h1g);
    fc_layer<300, 300, 0, false><<<75, 256, 0, stream>>>(h1g, fc2w, fc2b, h2g);
    fc_layer<300, 100, 0, false><<<25, 256, 0, stream>>>(h2g, fc3w, fc3b, h3g);
    fc_layer<100,  50, 0, false><<<13, 256, 0, stream>>>(h3g, fc4w, fc4b, h4g);
    fc_layer< 50,   9, 1, false><<< 3, 256, 0, stream>>>(h4g, fow,  fob,  out);
}

// Round 8
// 471.927 us; speedup vs baseline: 1.1320x; 1.1320x over previous
//
#include <hip/hip_runtime.h>
#include <math.h>

#define NNODES 38400
#define KNBR 8
#define BK 32

typedef __attribute__((ext_vector_type(8))) short bf16x8;
typedef __attribute__((ext_vector_type(4))) short short4v;
typedef __attribute__((ext_vector_type(4))) float f32x4;

// Round-to-nearest-even split of fp32 into hi+lo bf16 (bit patterns).
static __device__ inline void split_bf16(float x, short& hi, short& lo) {
    unsigned u = __float_as_uint(x);
    unsigned r = (u + 0x7FFFu + ((u >> 16) & 1u)) & 0xFFFF0000u;
    hi = (short)(r >> 16);
    float rem = x - __uint_as_float(r);
    unsigned u2 = __float_as_uint(rem);
    unsigned r2 = (u2 + 0x7FFFu + ((u2 >> 16) & 1u));
    lo = (short)(r2 >> 16);
}

// Swizzled LDS element offset: row r (0..127) of 32 bf16, 16B chunk c (0..3),
// rotated by (r>>1)&3 -> ds_read_b128 across 16 rows is <=2-way (free).
static __device__ inline int lds_off(int r, int c) {
    return r * 32 + (((c + (r >> 1)) & 3) << 3);
}

// Async global->LDS, 16B per lane. LDS dest is wave-uniform base + lane*16.
static __device__ inline void gload16(const short* g, short* l) {
    __builtin_amdgcn_global_load_lds(
        (const __attribute__((address_space(1))) unsigned*)g,
        (__attribute__((address_space(3))) unsigned*)l, 16, 0, 0);
}

// ---- MFMA GEMM, global_load_lds staging, branch-free padded B ------------
// Y[M, ldY] = A[M,Kp-planes] @ Wcat[ldY rows, Kp-planes]^T (hi/lo split,
// 3 MFMAs). ldY multiple of 128; every output line fully stored.
__global__ __launch_bounds__(256) void gemm_lds(
    const short* __restrict__ Ahi, const short* __restrict__ Alo,
    int Kp, int nk,
    const short* __restrict__ Bhi, const short* __restrict__ Blo,
    int ldY, float* __restrict__ Y)
{
    const int row0 = blockIdx.x * 128;
    const int col0 = blockIdx.y * 128;
    const int tid = threadIdx.x;
    const int lane = tid & 63, wid = tid >> 6;
    const int wm = wid >> 1, wn = wid & 1;

    __shared__ short Ah_s[128 * 32];
    __shared__ short Al_s[128 * 32];
    __shared__ short Bh_s[128 * 32];
    __shared__ short Bl_s[128 * 32];

    // staging geometry: wave stages local rows [wid*32, wid*32+32),
    // two 1024B instructions per plane (16 rows each).
    const int li = lane >> 2;          // row within 16-row group
    const int lc = lane & 3;           // physical 16B chunk
    const int r0 = wid * 32 + li;      // local rows for the two groups
    const int r1 = r0 + 16;
    const int c0 = (lc - (r0 >> 1)) & 3;   // logical chunk stored here
    const int c1 = (lc - (r1 >> 1)) & 3;

    const short* sAh0 = Ahi + (size_t)(row0 + r0) * Kp + c0 * 8;
    const short* sAh1 = Ahi + (size_t)(row0 + r1) * Kp + c1 * 8;
    const short* sAl0 = Alo + (size_t)(row0 + r0) * Kp + c0 * 8;
    const short* sAl1 = Alo + (size_t)(row0 + r1) * Kp + c1 * 8;
    const short* sBh0 = Bhi + (size_t)(col0 + r0) * Kp + c0 * 8;
    const short* sBh1 = Bhi + (size_t)(col0 + r1) * Kp + c1 * 8;
    const short* sBl0 = Blo + (size_t)(col0 + r0) * Kp + c0 * 8;
    const short* sBl1 = Blo + (size_t)(col0 + r1) * Kp + c1 * 8;

    short* dA0 = &Ah_s[(wid * 32) * 32];
    short* dA1 = &Ah_s[(wid * 32 + 16) * 32];
    short* dAl0 = &Al_s[(wid * 32) * 32];
    short* dAl1 = &Al_s[(wid * 32 + 16) * 32];
    short* dB0 = &Bh_s[(wid * 32) * 32];
    short* dB1 = &Bh_s[(wid * 32 + 16) * 32];
    short* dBl0 = &Bl_s[(wid * 32) * 32];
    short* dBl1 = &Bl_s[(wid * 32 + 16) * 32];

    f32x4 acc[4][4] = {};

    for (int ks = 0; ks < nk; ++ks) {
        const int ko = ks * BK;
        __syncthreads();                 // prior reads done before overwrite
        gload16(sAh0 + ko, dA0);  gload16(sAh1 + ko, dA1);
        gload16(sAl0 + ko, dAl0); gload16(sAl1 + ko, dAl1);
        gload16(sBh0 + ko, dB0);  gload16(sBh1 + ko, dB1);
        gload16(sBl0 + ko, dBl0); gload16(sBl1 + ko, dBl1);
        __syncthreads();                 // drains vmcnt before reads

        const int fr = lane & 15, g = lane >> 4;
        bf16x8 bh[4], bl[4];
#pragma unroll
        for (int f = 0; f < 4; ++f) {
            int bc = wn * 64 + f * 16 + fr;
            bh[f] = *(const bf16x8*)&Bh_s[lds_off(bc, g)];
            bl[f] = *(const bf16x8*)&Bl_s[lds_off(bc, g)];
        }
#pragma unroll
        for (int fm = 0; fm < 4; ++fm) {
            int ar = wm * 64 + fm * 16 + fr;
            bf16x8 ah = *(const bf16x8*)&Ah_s[lds_off(ar, g)];
            bf16x8 al = *(const bf16x8*)&Al_s[lds_off(ar, g)];
#pragma unroll
            for (int fn = 0; fn < 4; ++fn) {
                // swapped operands: fragments hold C^T (col-major per lane)
                acc[fm][fn] = __builtin_amdgcn_mfma_f32_16x16x32_bf16(
                    bh[fn], ah, acc[fm][fn], 0, 0, 0);
                acc[fm][fn] = __builtin_amdgcn_mfma_f32_16x16x32_bf16(
                    bl[fn], ah, acc[fm][fn], 0, 0, 0);
                acc[fm][fn] = __builtin_amdgcn_mfma_f32_16x16x32_bf16(
                    bh[fn], al, acc[fm][fn], 0, 0, 0);
            }
        }
    }

    // unconditional full-line stores (pad cols are exact zeros)
#pragma unroll
    for (int fm = 0; fm < 4; ++fm) {
        int row = row0 + wm * 64 + fm * 16 + (lane & 15);
#pragma unroll
        for (int fn = 0; fn < 4; ++fn) {
            int col = col0 + wn * 64 + fn * 16 + (lane >> 4) * 4;
            *(f32x4*)(Y + (size_t)row * ldY + col) = acc[fm][fn];
        }
    }
}

// ---- split X (fp32 [N][50] -> hi/lo bf16 planes [N][64], zero-padded) ----
__global__ __launch_bounds__(256) void split_x(
    const float* __restrict__ X, short* __restrict__ Hhi, short* __restrict__ Hlo)
{
    const int total = NNODES * 16;
    for (int idx = blockIdx.x * 256 + threadIdx.x; idx < total;
         idx += gridDim.x * 256) {
        int n = idx >> 4, c = (idx & 15) << 2;
        short4v hi, lo;
#pragma unroll
        for (int j = 0; j < 4; ++j) {
            int e = c + j;
            float v = (e < 50) ? X[(size_t)n * 50 + e] : 0.f;
            short h, l; split_bf16(v, h, l);
            hi[j] = h; lo[j] = l;
        }
        *(short4v*)&Hhi[(size_t)n * 64 + c] = hi;
        *(short4v*)&Hlo[(size_t)n * 64 + c] = lo;
    }
}

// ---- build padded Wcat planes: rows [theta D | pad | phi D | pad] --------
// chunkRows rows per chunk; chunk ch uses theta/phi rows [ch*Dchunk, +D).
__global__ __launch_bounds__(256) void split_wcat(
    const float* __restrict__ tw, const float* __restrict__ pw,
    int Ci, int Kp, int kpshift, int rows, int D, int phi,
    int chunkRows, int Dchunk,
    short* __restrict__ hi, short* __restrict__ lo)
{
    const int kp4 = Kp >> 2;
    const int total = rows * kp4;
    for (int idx = blockIdx.x * 256 + threadIdx.x; idx < total;
         idx += gridDim.x * 256) {
        const int r = idx >> (kpshift - 2);
        const int c = (idx & (kp4 - 1)) << 2;
        const int ch = r / chunkRows;
        const int w = r - ch * chunkRows;
        const float* src = nullptr;
        if (w < D) src = tw + (size_t)(ch * Dchunk + w) * Ci;
        else if (w >= phi && w < phi + D)
            src = pw + (size_t)(ch * Dchunk + (w - phi)) * Ci;
        short4v h4 = {}, l4 = {};
        if (src) {
#pragma unroll
            for (int j = 0; j < 4; ++j) {
                int e = c + j;
                float v = (e < Ci) ? src[e] : 0.f;
                short h, l; split_bf16(v, h, l);
                h4[j] = h; l4[j] = l;
            }
        }
        *(short4v*)&hi[(size_t)r * Kp + c] = h4;
        *(short4v*)&lo[(size_t)r * Kp + c] = l4;
    }
}

// ---- EdgeConv epilogue (layers 1-2): node-major flat, full-line writes ---
template <int LDY, int PHI, int CO, int KP, int KPSHIFT>
__global__ __launch_bounds__(256) void epi_flat(
    const float* __restrict__ Y, const int* __restrict__ nbr,
    const float* __restrict__ tb, const float* __restrict__ pb,
    short* __restrict__ Hhi, short* __restrict__ Hlo)
{
    const int total = NNODES << (KPSHIFT - 2);
    for (int idx = blockIdx.x * 256 + threadIdx.x; idx < total;
         idx += gridDim.x * 256) {
        const int n = idx >> (KPSHIFT - 2);
        const int c = (idx & ((KP >> 2) - 1)) << 2;
        if (c >= CO) {   // zero pad region of H planes
            short4v z = {};
            *(short4v*)&Hhi[(size_t)n * KP + c] = z;
            *(short4v*)&Hlo[(size_t)n * KP + c] = z;
            continue;
        }
        const int* jn = nbr + n * KNBR;
        float4 m = make_float4(-INFINITY, -INFINITY, -INFINITY, -INFINITY);
#pragma unroll
        for (int k = 0; k < KNBR; ++k) {
            float4 v = *(const float4*)(Y + (size_t)jn[k] * LDY + c);
            m.x = fmaxf(m.x, v.x); m.y = fmaxf(m.y, v.y);
            m.z = fmaxf(m.z, v.z); m.w = fmaxf(m.w, v.w);
        }
        float4 yt = *(const float4*)(Y + (size_t)n * LDY + c);
        float4 yp = *(const float4*)(Y + (size_t)n * LDY + PHI + c);
        float4 b1 = *(const float4*)(tb + c);
        float4 b2 = *(const float4*)(pb + c);
        float o0 = tanhf(m.x - yt.x + b1.x + yp.x + b2.x);
        float o1 = tanhf(m.y - yt.y + b1.y + yp.y + b2.y);
        float o2 = tanhf(m.z - yt.z + b1.z + yp.z + b2.z);
        float o3 = tanhf(m.w - yt.w + b1.w + yp.w + b2.w);
        short4v hi, lo;
        short h, l;
        split_bf16(o0, h, l); hi[0] = h; lo[0] = l;
        split_bf16(o1, h, l); hi[1] = h; lo[1] = l;
        split_bf16(o2, h, l); hi[2] = h; lo[2] = l;
        split_bf16(o3, h, l); hi[3] = h; lo[3] = l;
        *(short4v*)&Hhi[(size_t)n * KP + c] = hi;
        *(short4v*)&Hlo[(size_t)n * KP + c] = lo;
    }
}

// ---- Layer-3 epilogue: 16 lanes/node, channel max -> gk[p*64+graph] ------
// D=120 per chunk, Y layout: theta cols 0..119, phi at 128..247, ld 256.
__global__ __launch_bounds__(256) void epi3_16(
    const float* __restrict__ Y,
    const int* __restrict__ nbr,
    const float* __restrict__ tb, const float* __restrict__ pb,
    float* __restrict__ gk, int first)
{
    const int node = blockIdx.x * 16 + (threadIdx.x >> 4);
    if (node >= NNODES) return;
    const int l16 = threadIdx.x & 15;
    const int* jn = nbr + node * KNBR;
    int j[KNBR];
#pragma unroll
    for (int k = 0; k < KNBR; ++k) j[k] = jn[k];
    float mx = -INFINITY;
#pragma unroll
    for (int it = 0; it < 2; ++it) {
        int c4 = l16 + it * 16;
        if (c4 >= 30) break;            // 120/4 chunks
        const int c = c4 << 2;
        float4 m = make_float4(-INFINITY, -INFINITY, -INFINITY, -INFINITY);
#pragma unroll
        for (int k = 0; k < KNBR; ++k) {
            float4 v = *(const float4*)(Y + (size_t)j[k] * 256 + c);
            m.x = fmaxf(m.x, v.x); m.y = fmaxf(m.y, v.y);
            m.z = fmaxf(m.z, v.z); m.w = fmaxf(m.w, v.w);
        }
        float4 yt = *(const float4*)(Y + (size_t)node * 256 + c);
        float4 yp = *(const float4*)(Y + (size_t)node * 256 + 128 + c);
        float4 b1 = *(const float4*)(tb + c);
        float4 b2 = *(const float4*)(pb + c);
        mx = fmaxf(mx, m.x - yt.x + b1.x + yp.x + b2.x);
        mx = fmaxf(mx, m.y - yt.y + b1.y + yp.y + b2.y);
        mx = fmaxf(mx, m.z - yt.z + b1.z + yp.z + b2.z);
        mx = fmaxf(mx, m.w - yt.w + b1.w + yp.w + b2.w);
    }
#pragma unroll
    for (int off = 1; off < 16; off <<= 1)
        mx = fmaxf(mx, __shfl_xor(mx, off));
    if (l16 == 0) {
        unsigned q = (unsigned)node * 0xAAAB / 0x40000;  // /600 (node<2^18... )
        int g = node / 600;
        int p = node - g * 600;
        (void)q;
        float* dst = &gk[p * 64 + g];
        *dst = first ? mx : fmaxf(*dst, mx);
    }
}

// ---- FC layer: channel-major activations [CIN][64], block = 4 o x 64 g ---
template <int CIN, int COUT, int ACT>
__global__ __launch_bounds__(256) void fc_layer(
    const float* __restrict__ in, const float* __restrict__ w,
    const float* __restrict__ b, float* __restrict__ out)
{
    const int o = blockIdx.x * 4 + (threadIdx.x >> 6);
    const int g = threadIdx.x & 63;
    if (o >= COUT) return;
    float s = b[o];
#pragma unroll 4
    for (int c = 0; c < CIN; ++c)
        s = fmaf(in[c * 64 + g], w[o * CIN + c], s);
    if (ACT == 0) out[o * 64 + g] = tanhf(s);
    else out[(size_t)g * COUT + o] = fminf(fmaxf(s, -2.f), 2.f);
}

extern "C" void kernel_launch(void* const* d_in, const int* in_sizes, int n_in,
                              void* d_out, int out_size, void* d_ws, size_t ws_size,
                              hipStream_t stream)
{
    const float* inputs = (const float*)d_in[0];
    const int*   nbr    = (const int*)d_in[1];
    const float* t1w = (const float*)d_in[2];  const float* t1b = (const float*)d_in[3];
    const float* p1w = (const float*)d_in[4];  const float* p1b = (const float*)d_in[5];
    const float* t2w = (const float*)d_in[6];  const float* t2b = (const float*)d_in[7];
    const float* p2w = (const float*)d_in[8];  const float* p2b = (const float*)d_in[9];
    const float* t3w = (const float*)d_in[10]; const float* t3b = (const float*)d_in[11];
    const float* p3w = (const float*)d_in[12]; const float* p3b = (const float*)d_in[13];
    const float* fc1w = (const float*)d_in[14]; const float* fc1b = (const float*)d_in[15];
    const float* fc2w = (const float*)d_in[16]; const float* fc2b = (const float*)d_in[17];
    const float* fc3w = (const float*)d_in[18]; const float* fc3b = (const float*)d_in[19];
    const float* fc4w = (const float*)d_in[20]; const float* fc4b = (const float*)d_in[21];
    const float* fow  = (const float*)d_in[22]; const float* fob  = (const float*)d_in[23];
    float* out = (float*)d_out;

    const int N = NNODES;
    const int Kp1 = 64, Kp2 = 128, Kp3 = 256;
    const int nk1 = 2, nk2 = 4, nk3 = 7;   // K iterated: 64 / 128 / 224

    char* ws = (char*)d_ws;
    size_t off = 0;
    auto alloc = [&](size_t bytes) {
        void* p = ws + off;
        off = (off + bytes + 255) & ~(size_t)255;
        return p;
    };
    short* Xhi  = (short*)alloc((size_t)N * Kp1 * 2);
    short* Xlo  = (short*)alloc((size_t)N * Kp1 * 2);
    short* H1hi = (short*)alloc((size_t)N * Kp2 * 2);
    short* H1lo = (short*)alloc((size_t)N * Kp2 * 2);
    short* H2hi = (short*)alloc((size_t)N * Kp3 * 2);
    short* H2lo = (short*)alloc((size_t)N * Kp3 * 2);
    short* W1h = (short*)alloc((size_t)256 * Kp1 * 2);
    short* W1l = (short*)alloc((size_t)256 * Kp1 * 2);
    short* W2h = (short*)alloc((size_t)512 * Kp2 * 2);
    short* W2l = (short*)alloc((size_t)512 * Kp2 * 2);
    short* W3h = (short*)alloc((size_t)1280 * Kp3 * 2);
    short* W3l = (short*)alloc((size_t)1280 * Kp3 * 2);
    float* gk  = (float*)alloc((size_t)600 * 64 * 4);
    float* h1g = (float*)alloc((size_t)300 * 64 * 4);
    float* h2g = (float*)alloc((size_t)300 * 64 * 4);
    float* h3g = (float*)alloc((size_t)100 * 64 * 4);
    float* h4g = (float*)alloc((size_t)50 * 64 * 4);
    float* Y   = (float*)alloc((size_t)N * 512 * 4);   // max ldY=512

    // ---- prep: split X, build padded Wcat planes ----
    split_x<<<2400, 256, 0, stream>>>(inputs, Xhi, Xlo);
    split_wcat<<<64, 256, 0, stream>>>(t1w, p1w, 50, Kp1, 6, 256, 100, 128,
                                       256, 0, W1h, W1l);
    split_wcat<<<256, 256, 0, stream>>>(t2w, p2w, 100, Kp2, 7, 512, 200, 256,
                                        512, 0, W2h, W2l);
    split_wcat<<<320, 256, 0, stream>>>(t3w, p3w, 200, Kp3, 8, 1280, 120, 128,
                                        256, 120, W3h, W3l);

    // ---- EdgeConv 1: K 64, Y[*,256] theta@0 phi@128 ----
    gemm_lds<<<dim3(300, 2), 256, 0, stream>>>(Xhi, Xlo, Kp1, nk1,
                                               W1h, W1l, 256, Y);
    epi_flat<256, 128, 100, 128, 7><<<2400, 256, 0, stream>>>(
        Y, nbr, t1b, p1b, H1hi, H1lo);

    // ---- EdgeConv 2: K 128, Y[*,512] theta@0 phi@256 ----
    gemm_lds<<<dim3(300, 4), 256, 0, stream>>>(H1hi, H1lo, Kp2, nk2,
                                               W2h, W2l, 512, Y);
    epi_flat<512, 256, 200, 256, 8><<<4800, 256, 0, stream>>>(
        Y, nbr, t2b, p2b, H2hi, H2lo);

    // ---- EdgeConv 3: 5 chunks of D=120, Y[*,256] theta@0 phi@128 ----
    for (int ch = 0; ch < 5; ++ch) {
        const int d0 = ch * 120;
        gemm_lds<<<dim3(300, 2), 256, 0, stream>>>(
            H2hi, H2lo, Kp3, nk3,
            W3h + (size_t)ch * 256 * Kp3, W3l + (size_t)ch * 256 * Kp3,
            256, Y);
        epi3_16<<<2400, 256, 0, stream>>>(Y, nbr, t3b + d0, p3b + d0, gk,
                                          ch == 0 ? 1 : 0);
    }

    // ---- FC head: channel-major chain ----
    fc_layer<600, 300, 0><<<75, 256, 0, stream>>>(gk,  fc1w, fc1b, h1g);
    fc_layer<300, 300, 0><<<75, 256, 0, stream>>>(h1g, fc2w, fc2b, h2g);
    fc_layer<300, 100, 0><<<25, 256, 0, stream>>>(h2g, fc3w, fc3b, h3g);
    fc_layer<100,  50, 0><<<13, 256, 0, stream>>>(h3g, fc4w, fc4b, h4g);
    fc_layer< 50,   9, 1><<< 3, 256, 0, stream>>>(h4g, fow,  fob,  out);
}